// Round 10
// baseline (239.162 us; speedup 1.0000x reference)
//
#include <hip/hip_runtime.h>
#include <math.h>

#define TPB 256
#define ATPB 512
#define QSCALE 0.1803368801111204f   // 0.125 * log2(e): folds 1/sqrt(dk) and exp->exp2

typedef __attribute__((ext_vector_type(8))) short bf16x8;
typedef __attribute__((ext_vector_type(8))) unsigned short u16x8;
typedef __attribute__((ext_vector_type(4))) float f32x4;
typedef __attribute__((ext_vector_type(16))) float f32x16;
typedef __attribute__((ext_vector_type(4))) unsigned int u32x4;
typedef unsigned short u16;
typedef unsigned int u32;

#define MFMA16(a, b, c) __builtin_amdgcn_mfma_f32_16x16x32_bf16((a), (b), (c), 0, 0, 0)
#define MFMA32(a, b, c) __builtin_amdgcn_mfma_f32_32x32x16_bf16((a), (b), (c), 0, 0, 0)

__device__ __forceinline__ u16 f2bf(float f) {           // RNE
    unsigned int u = __float_as_uint(f);
    return (u16)((u + 0x7FFFu + ((u >> 16) & 1u)) >> 16);
}
__device__ __forceinline__ float bf2f(u16 h) {
    return __uint_as_float(((unsigned int)h) << 16);
}

// ---------------------------------------------------------------------------
// Pre-split fp32 -> (hi,lo) bf16. 8 elems/thread.
// ---------------------------------------------------------------------------
__global__ __launch_bounds__(TPB)
void presplit(const float* __restrict__ in, u16* __restrict__ oh,
              u16* __restrict__ ol, float scale)
{
    size_t i = ((size_t)blockIdx.x * TPB + threadIdx.x) * 8;
    float4 a = *reinterpret_cast<const float4*>(in + i);
    float4 b = *reinterpret_cast<const float4*>(in + i + 4);
    float v[8] = {a.x, a.y, a.z, a.w, b.x, b.y, b.z, b.w};
    u16x8 hv, lv;
    #pragma unroll
    for (int k = 0; k < 8; ++k) {
        float s = v[k] * scale;
        u16 h = f2bf(s);
        hv[k] = h;
        lv[k] = f2bf(s - bf2f(h));
    }
    *reinterpret_cast<u16x8*>(oh + i) = hv;
    *reinterpret_cast<u16x8*>(ol + i) = lv;
}

// 4 weights [512][512] -> concatenated hi/lo, Wq scaled by QSCALE.
__global__ __launch_bounds__(TPB)
void presplit_w(const float* __restrict__ w0, const float* __restrict__ w1,
                const float* __restrict__ w2, const float* __restrict__ w3,
                u16* __restrict__ WH, u16* __restrict__ WL)
{
    int y = blockIdx.y;
    const float* src = (y == 0) ? w0 : (y == 1) ? w1 : (y == 2) ? w2 : w3;
    float sc = (y == 0) ? QSCALE : 1.0f;
    size_t base = (size_t)y * 262144;
    size_t i = ((size_t)blockIdx.x * TPB + threadIdx.x) * 8;
    float4 a = *reinterpret_cast<const float4*>(src + i);
    float4 b = *reinterpret_cast<const float4*>(src + i + 4);
    float v[8] = {a.x, a.y, a.z, a.w, b.x, b.y, b.z, b.w};
    u16x8 hv, lv;
    #pragma unroll
    for (int k = 0; k < 8; ++k) {
        float s = v[k] * sc;
        u16 h = f2bf(s);
        hv[k] = h;
        lv[k] = f2bf(s - bf2f(h));
    }
    *reinterpret_cast<u16x8*>(WH + base + i) = hv;
    *reinterpret_cast<u16x8*>(WL + base + i) = lv;
}

// ---------------------------------------------------------------------------
// Compact Tonnetz mask: weights as bf16 in the 32x32 MFMA S^T D-layout.
// Period 144 in q and k -> 9x9 distinct 64x64 tiles (648 KB, L2-resident).
// ---------------------------------------------------------------------------
__global__ __launch_bounds__(TPB)
void mask_pre(u32* __restrict__ mws)
{
    int bid = blockIdx.x;            // 0..80
    int mq9 = bid / 9, mk9 = bid % 9;
    int t = threadIdx.x, w = t >> 6, l = t & 63, lh = l >> 5, l31 = l & 31;
    int q = mq9 * 16 + (w & 1) * 32 + l31;
    int qx = q % 12, qy = (q / 12) % 12;
    u32 words[8];
    #pragma unroll
    for (int jr = 0; jr < 8; ++jr) {
        u16 wb[2];
        #pragma unroll
        for (int e = 0; e < 2; ++e) {
            int r = jr * 2 + e;
            int key = mk9 * 16 + (w >> 1) * 32 + (r & 3) + 8 * (r >> 2) + 4 * lh;
            int kx = key % 12, ky = (key / 12) % 12;
            int dx = qx - kx; dx = dx < 0 ? -dx : dx; dx = dx < 12 - dx ? dx : 12 - dx;
            int dy = qy - ky; dy = dy < 0 ? -dy : dy; dy = dy < 12 - dy ? dy : 12 - dy;
            int d = dx + dy;
            float wgt = (d <= 2) ? 1.0f : __expf(-(float)d);
            wb[e] = f2bf(wgt);
        }
        words[jr] = (u32)wb[0] | ((u32)wb[1] << 16);
    }
    u32* dst = &mws[(size_t)((bid * 4 + w) * 64 + l) * 8];
    #pragma unroll
    for (int jr = 0; jr < 8; ++jr) dst[jr] = words[jr];
}

// ---------------------------------------------------------------------------
// Split-bf16 GEMM, PRE-SPLIT operands (round-6/8 proven loop + fused epilogue)
// mode 0: fp32 out [8192][512] (bias b0)
// mode 9: QKV fused (B = [1536][512] concat), proj = n0>>9:
//         0 -> Q hi/lo [b][h][t][d] (bias b0 * QSCALE)
//         1 -> K bf16  [b][h][t][d] (bias b1)
//         2 -> V bf16 transposed [b][h][d][t] (bias b2)
// ---------------------------------------------------------------------------
__global__ __launch_bounds__(TPB)
void gemm_pre(const u16* __restrict__ Ah_g, const u16* __restrict__ Al_g,
              const u16* __restrict__ Bh_g, const u16* __restrict__ Bl_g,
              const float* __restrict__ b0, const float* __restrict__ b1,
              const float* __restrict__ b2,
              float* __restrict__ outf, u16* __restrict__ o1h,
              u16* __restrict__ o1l, u16* __restrict__ o2,
              u16* __restrict__ o3, int mode)
{
    __shared__ __align__(16) u16 AhS[128][40], AlS[128][40];
    __shared__ __align__(16) u16 BhS[128][40], BlS[128][40];

    const int t  = threadIdx.x;
    const int m0 = blockIdx.x * 128;
    const int n0 = blockIdx.y * 128;
    const int wv = t >> 6, l = t & 63, lr = l & 15, lg = l >> 4;
    const int wm = (wv >> 1) * 64, wn = (wv & 1) * 64;

    f32x4 acc[4][4];
    #pragma unroll
    for (int i = 0; i < 4; ++i)
        #pragma unroll
        for (int j = 0; j < 4; ++j) acc[i][j] = f32x4{};

    for (int k0 = 0; k0 < 512; k0 += 32) {
        __syncthreads();
        #pragma unroll
        for (int p = 0; p < 2; ++p) {
            int cc = t + TPB * p;
            int r = cc >> 2, c8 = (cc & 3) << 3;
            *reinterpret_cast<bf16x8*>(&AhS[r][c8]) =
                *reinterpret_cast<const bf16x8*>(&Ah_g[(size_t)(m0 + r) * 512 + k0 + c8]);
            *reinterpret_cast<bf16x8*>(&AlS[r][c8]) =
                *reinterpret_cast<const bf16x8*>(&Al_g[(size_t)(m0 + r) * 512 + k0 + c8]);
            *reinterpret_cast<bf16x8*>(&BhS[r][c8]) =
                *reinterpret_cast<const bf16x8*>(&Bh_g[(size_t)(n0 + r) * 512 + k0 + c8]);
            *reinterpret_cast<bf16x8*>(&BlS[r][c8]) =
                *reinterpret_cast<const bf16x8*>(&Bl_g[(size_t)(n0 + r) * 512 + k0 + c8]);
        }
        __syncthreads();

        bf16x8 afh[4], afl[4], bfh[4], bfl[4];
        #pragma unroll
        for (int mi = 0; mi < 4; ++mi) {
            afh[mi] = *reinterpret_cast<const bf16x8*>(&AhS[wm + mi*16 + lr][lg*8]);
            afl[mi] = *reinterpret_cast<const bf16x8*>(&AlS[wm + mi*16 + lr][lg*8]);
        }
        #pragma unroll
        for (int ni = 0; ni < 4; ++ni) {
            bfh[ni] = *reinterpret_cast<const bf16x8*>(&BhS[wn + ni*16 + lr][lg*8]);
            bfl[ni] = *reinterpret_cast<const bf16x8*>(&BlS[wn + ni*16 + lr][lg*8]);
        }
        #pragma unroll
        for (int mi = 0; mi < 4; ++mi)
            #pragma unroll
            for (int ni = 0; ni < 4; ++ni) {
                acc[mi][ni] = MFMA16(afh[mi], bfh[ni], acc[mi][ni]);
                acc[mi][ni] = MFMA16(afh[mi], bfl[ni], acc[mi][ni]);
                acc[mi][ni] = MFMA16(afl[mi], bfh[ni], acc[mi][ni]);
            }
    }

    // epilogue: D frag -> (row = mi*16 + lg*4 + j, col = ni*16 + lr)
    int emode = mode;
    const float* bias = b0;
    float bsc = 1.0f;
    if (mode == 9) {
        int proj = n0 >> 9;
        emode = (proj == 0) ? 1 : (proj == 1) ? 2 : 3;
        bias = (proj == 0) ? b0 : (proj == 1) ? b1 : b2;
        bsc = (proj == 0) ? QSCALE : 1.0f;
    }
    #pragma unroll
    for (int ni = 0; ni < 4; ++ni) {
        int gn = n0 + wn + ni*16 + lr;
        int nn = gn & 511;
        float bb = bias[nn] * bsc;
        #pragma unroll
        for (int mi = 0; mi < 4; ++mi) {
            #pragma unroll
            for (int j = 0; j < 4; ++j) {
                int gm = m0 + wm + mi*16 + lg*4 + j;
                float v = acc[mi][ni][j] + bb;
                if (emode == 0) {
                    outf[(size_t)gm * 512 + gn] = v;
                } else {
                    int b = gm >> 11, tt = gm & 2047, hh = nn >> 6, d = nn & 63;
                    if (emode == 1) {
                        u16 h16 = f2bf(v);
                        size_t o = (((size_t)(b*8 + hh) * 2048) + tt) * 64 + d;
                        o1h[o] = h16;
                        o1l[o] = f2bf(v - bf2f(h16));
                    } else if (emode == 2) {
                        o2[(((size_t)(b*8 + hh) * 2048) + tt) * 64 + d] = f2bf(v);
                    } else {
                        o3[(((size_t)(b*8 + hh) * 64) + d) * 2048 + tt] = f2bf(v);
                    }
                }
            }
        }
    }
}

// ---------------------------------------------------------------------------
// Flash attention, 8 waves x 128 q-rows/block, NO K/V LDS staging and NO
// main-loop barriers: K/V per head is L2-resident (256+256 KB), so each wave
// reads its MFMA fragments directly from global (L1 catches the 4x same-kh
// redundancy). Waves free-run across tiles; latency hidden by 16 waves/CU
// TLP instead of intra-block pipelining. Load order per tile: K-frags ->
// mask -> V-frags, so vmcnt lets QK^T start with V/mask still in flight.
// Fragment math, exp path, pack/exchange, merge: identical to round 9.
// LDS only for the final O merge (32 KB scratch).
// ---------------------------------------------------------------------------
__global__ __launch_bounds__(ATPB)
void attn32(const u16* __restrict__ Qh_g, const u16* __restrict__ Ql_g,
            const u16* __restrict__ K_g,  const u16* __restrict__ Vt_g,
            const u32* __restrict__ mws,
            u16* __restrict__ AOh, u16* __restrict__ AOl)
{
    __shared__ float OSC[128][64];       // 32 KB merge scratch
    __shared__ float SC[8][64];
    __shared__ float ILS[128];

    const int t = threadIdx.x;
    int id  = blockIdx.x;                 // 512 blocks: 8 XCD x 4 bh x 16 q-tiles
    int xcd = id & 7, seq = id >> 3;
    int bh  = xcd * 4 + (seq >> 4);
    int qt  = seq & 15;
    const int q0 = qt * 128;
    const int b = bh >> 3, h = bh & 7;
    const int w = t >> 6, l = t & 63, lh = l >> 5, l31 = l & 31;
    const int qg = w >> 1, kh = w & 1;
    const int mq9 = ((q0 + qg * 32) % 144) >> 4;

    // Q B-fragments in registers: col q = q0 + qg*32 + l31, k = ks*16 + lh*8 + j
    const u16* Qhb = Qh_g + ((size_t)bh * 2048 + q0 + qg * 32 + l31) * 64;
    const u16* Qlb = Ql_g + ((size_t)bh * 2048 + q0 + qg * 32 + l31) * 64;
    bf16x8 qfh[4], qfl[4];
    #pragma unroll
    for (int ks = 0; ks < 4; ++ks) {
        qfh[ks] = *reinterpret_cast<const bf16x8*>(&Qhb[ks * 16 + lh * 8]);
        qfl[ks] = *reinterpret_cast<const bf16x8*>(&Qlb[ks * 16 + lh * 8]);
    }

    // per-lane global fragment bases (advance by 64 keys per tile)
    const u16* Kf = K_g  + (size_t)bh * 2048 * 64 + (size_t)(kh * 32 + l31) * 64 + lh * 8;
    const u16* Vf0 = Vt_g + (size_t)bh * 64 * 2048 + (size_t)l31 * 2048 + kh * 32 + lh * 8;
    const u16* Vf1 = Vf0 + 32 * 2048;

    f32x16 o0 = {}, o1 = {};
    float lrow = 0.f;

    for (int kt = 0; kt < 32; ++kt) {
        const size_t koff = (size_t)kt * 64;

        // ---- issue K-fragment loads (4 x 16B), then mask, then V (8 x 16B) ----
        bf16x8 kf0 = *reinterpret_cast<const bf16x8*>(&Kf[koff * 64 + 0]);
        bf16x8 kf1 = *reinterpret_cast<const bf16x8*>(&Kf[koff * 64 + 16]);
        bf16x8 kf2 = *reinterpret_cast<const bf16x8*>(&Kf[koff * 64 + 32]);
        bf16x8 kf3 = *reinterpret_cast<const bf16x8*>(&Kf[koff * 64 + 48]);

        int mk9 = (4 * kt) % 9;
        const u32* mp = &mws[(size_t)((((mq9 * 9 + mk9) * 4 + (kh << 1)) * 64 + l)) * 8];
        u32x4 mwa = *reinterpret_cast<const u32x4*>(mp);
        u32x4 mwb = *reinterpret_cast<const u32x4*>(mp + 4);

        bf16x8 vf00 = *reinterpret_cast<const bf16x8*>(&Vf0[koff + 0]);
        bf16x8 vf01 = *reinterpret_cast<const bf16x8*>(&Vf0[koff + 16]);
        bf16x8 vf10 = *reinterpret_cast<const bf16x8*>(&Vf1[koff + 0]);
        bf16x8 vf11 = *reinterpret_cast<const bf16x8*>(&Vf1[koff + 16]);

        // ---- S^T = K (Qh^T + Ql^T) ----
        f32x16 st = {};
        __builtin_amdgcn_s_setprio(1);
        st = MFMA32(kf0, qfh[0], st);
        st = MFMA32(kf0, qfl[0], st);
        st = MFMA32(kf1, qfh[1], st);
        st = MFMA32(kf1, qfl[1], st);
        st = MFMA32(kf2, qfh[2], st);
        st = MFMA32(kf2, qfl[2], st);
        st = MFMA32(kf3, qfh[3], st);
        st = MFMA32(kf3, qfl[3], st);
        __builtin_amdgcn_s_setprio(0);

        // ---- p = exp2(s * w), bf16 weights unpacked from packed words ----
        float p[16];
        #pragma unroll
        for (int r = 0; r < 16; ++r) {
            u32 word = (r < 8) ? mwa[r >> 1] : mwb[(r >> 1) - 4];
            u32 bits = (r & 1) ? (word & 0xFFFF0000u) : (word << 16);
            float wgt = __uint_as_float(bits);
            p[r] = exp2f(st[r] * wgt);
            lrow += p[r];
        }

        // ---- PV: pack P (cvt_pk) + shfl_xor(32) half-exchange ----
        __builtin_amdgcn_s_setprio(1);
        #pragma unroll
        for (int ks = 0; ks < 2; ++ks) {
            const int base = ks * 8;
            u32 pk01, pk23, pk45, pk67;
            asm("v_cvt_pk_bf16_f32 %0, %1, %2" : "=v"(pk01) : "v"(p[base + 0]), "v"(p[base + 1]));
            asm("v_cvt_pk_bf16_f32 %0, %1, %2" : "=v"(pk23) : "v"(p[base + 2]), "v"(p[base + 3]));
            asm("v_cvt_pk_bf16_f32 %0, %1, %2" : "=v"(pk45) : "v"(p[base + 4]), "v"(p[base + 5]));
            asm("v_cvt_pk_bf16_f32 %0, %1, %2" : "=v"(pk67) : "v"(p[base + 6]), "v"(p[base + 7]));
            u32 x01 = __shfl_xor(pk01, 32, 64);
            u32 x23 = __shfl_xor(pk23, 32, 64);
            u32 x45 = __shfl_xor(pk45, 32, 64);
            u32 x67 = __shfl_xor(pk67, 32, 64);
            u32 s01 = lh ? x45 : pk01;
            u32 s23 = lh ? x67 : pk23;
            u32 s45 = lh ? pk45 : x01;
            u32 s67 = lh ? pk67 : x23;
            u32x4 pw = {s01, s23, s45, s67};
            bf16x8 pa = __builtin_bit_cast(bf16x8, pw);
            bf16x8 v0 = ks ? vf01 : vf00;
            bf16x8 v1 = ks ? vf11 : vf10;
            o0 = MFMA32(pa, v0, o0);
            o1 = MFMA32(pa, v1, o1);
        }
        __builtin_amdgcn_s_setprio(0);
    }

    // ---- merge: lrow across (lane-half, key-half); O across key-halves ----
    SC[w][l] = lrow;
    __syncthreads();
    if (kh == 1) {
        #pragma unroll
        for (int r = 0; r < 16; ++r) {
            int q = qg * 32 + (r & 3) + 8 * (r >> 2) + 4 * lh;
            OSC[q][l31]      = o0[r];
            OSC[q][32 + l31] = o1[r];
        }
    } else if (l < 32) {
        float s = SC[qg*2][l31] + SC[qg*2][l31 + 32] + SC[qg*2 + 1][l31] + SC[qg*2 + 1][l31 + 32];
        ILS[qg * 32 + l31] = 1.0f / s;
    }
    __syncthreads();
    if (kh == 0) {
        #pragma unroll
        for (int r = 0; r < 16; ++r) {
            int q = qg * 32 + (r & 3) + 8 * (r >> 2) + 4 * lh;
            float il = ILS[q];
            float v0 = (o0[r] + OSC[q][l31]) * il;
            float v1 = (o1[r] + OSC[q][32 + l31]) * il;
            size_t row = (size_t)b * 2048 + q0 + q;
            size_t off0 = row * 512 + h * 64 + l31;
            u16 h0v = f2bf(v0);
            AOh[off0] = h0v;
            AOl[off0] = f2bf(v0 - bf2f(h0v));
            u16 h1v = f2bf(v1);
            AOh[off0 + 32] = h1v;
            AOl[off0 + 32] = f2bf(v1 - bf2f(h1v));
        }
    }
}

// ---------------------------------------------------------------------------
extern "C" void kernel_launch(void* const* d_in, const int* in_sizes, int n_in,
                              void* d_out, int out_size, void* d_ws, size_t ws_size,
                              hipStream_t stream)
{
    (void)in_sizes; (void)n_in; (void)out_size; (void)ws_size;
    const float* x  = (const float*)d_in[0];
    const float* Wq = (const float*)d_in[1];
    const float* bq = (const float*)d_in[2];
    const float* Wk = (const float*)d_in[3];
    const float* bk = (const float*)d_in[4];
    const float* Wv = (const float*)d_in[5];
    const float* bv = (const float*)d_in[6];
    const float* Wo = (const float*)d_in[7];
    const float* bo = (const float*)d_in[8];
    float* out = (float*)d_out;

    // workspace (~53 MB of >=64 MB proven):
    u16* Xh = (u16*)d_ws;                 // 8 MB (reused as AOh)
    u16* Xl = Xh + 4194304;               // 8 MB (reused as AOl)
    u16* WH = Xl + 4194304;               // 2 MB
    u16* WL = WH + 1048576;               // 2 MB
    u16* Qh = WL + 1048576;               // 8 MB
    u16* Ql = Qh + 4194304;               // 8 MB
    u16* Kh = Ql + 4194304;               // 8 MB
    u16* Vt = Kh + 4194304;               // 8 MB
    u32* MW = (u32*)(Vt + 4194304);       // 648 KB (bf16 compact mask)

    presplit<<<2048, TPB, 0, stream>>>(x, Xh, Xl, 1.0f);
    presplit_w<<<dim3(128, 4), TPB, 0, stream>>>(Wq, Wk, Wv, Wo, WH, WL);
    mask_pre<<<81, TPB, 0, stream>>>(MW);

    // fused QKV projection: 768 blocks, 40 KB LDS -> ~4 blocks/CU overlap
    gemm_pre<<<dim3(64, 12), TPB, 0, stream>>>(
        Xh, Xl, WH, WL, bq, bk, bv,
        nullptr, Qh, Ql, Kh, Vt, 9);

    // 8-wave attention: 512 blocks x 512 threads, barrier-free main loop
    attn32<<<512, ATPB, 0, stream>>>(Qh, Ql, Kh, Vt, MW, Xh, Xl);

    // output projection
    gemm_pre<<<dim3(64, 4), TPB, 0, stream>>>(
        Xh, Xl, WH + 786432, WL + 786432, bo, nullptr, nullptr,
        out, nullptr, nullptr, nullptr, nullptr, 0);
}

// Round 11
// 192.808 us; speedup vs baseline: 1.2404x; 1.2404x over previous
//
#include <hip/hip_runtime.h>
#include <math.h>

#define TPB 256
#define ATPB 512
#define QSCALE 0.1803368801111204f   // 0.125 * log2(e): folds 1/sqrt(dk) and exp->exp2

typedef __attribute__((ext_vector_type(8))) short bf16x8;
typedef __attribute__((ext_vector_type(8))) unsigned short u16x8;
typedef __attribute__((ext_vector_type(4))) float f32x4;
typedef __attribute__((ext_vector_type(16))) float f32x16;
typedef __attribute__((ext_vector_type(4))) unsigned int u32x4;
typedef unsigned short u16;
typedef unsigned int u32;

#define MFMA16(a, b, c) __builtin_amdgcn_mfma_f32_16x16x32_bf16((a), (b), (c), 0, 0, 0)
#define MFMA32(a, b, c) __builtin_amdgcn_mfma_f32_32x32x16_bf16((a), (b), (c), 0, 0, 0)

__device__ __forceinline__ u16 f2bf(float f) {           // RNE
    unsigned int u = __float_as_uint(f);
    return (u16)((u + 0x7FFFu + ((u >> 16) & 1u)) >> 16);
}
__device__ __forceinline__ float bf2f(u16 h) {
    return __uint_as_float(((unsigned int)h) << 16);
}

// ---------------------------------------------------------------------------
// Pre-split fp32 -> (hi,lo) bf16. 8 elems/thread.
// ---------------------------------------------------------------------------
__global__ __launch_bounds__(TPB)
void presplit(const float* __restrict__ in, u16* __restrict__ oh,
              u16* __restrict__ ol, float scale)
{
    size_t i = ((size_t)blockIdx.x * TPB + threadIdx.x) * 8;
    float4 a = *reinterpret_cast<const float4*>(in + i);
    float4 b = *reinterpret_cast<const float4*>(in + i + 4);
    float v[8] = {a.x, a.y, a.z, a.w, b.x, b.y, b.z, b.w};
    u16x8 hv, lv;
    #pragma unroll
    for (int k = 0; k < 8; ++k) {
        float s = v[k] * scale;
        u16 h = f2bf(s);
        hv[k] = h;
        lv[k] = f2bf(s - bf2f(h));
    }
    *reinterpret_cast<u16x8*>(oh + i) = hv;
    *reinterpret_cast<u16x8*>(ol + i) = lv;
}

// 4 weights [512][512] -> concatenated hi/lo, Wq scaled by QSCALE.
__global__ __launch_bounds__(TPB)
void presplit_w(const float* __restrict__ w0, const float* __restrict__ w1,
                const float* __restrict__ w2, const float* __restrict__ w3,
                u16* __restrict__ WH, u16* __restrict__ WL)
{
    int y = blockIdx.y;
    const float* src = (y == 0) ? w0 : (y == 1) ? w1 : (y == 2) ? w2 : w3;
    float sc = (y == 0) ? QSCALE : 1.0f;
    size_t base = (size_t)y * 262144;
    size_t i = ((size_t)blockIdx.x * TPB + threadIdx.x) * 8;
    float4 a = *reinterpret_cast<const float4*>(src + i);
    float4 b = *reinterpret_cast<const float4*>(src + i + 4);
    float v[8] = {a.x, a.y, a.z, a.w, b.x, b.y, b.z, b.w};
    u16x8 hv, lv;
    #pragma unroll
    for (int k = 0; k < 8; ++k) {
        float s = v[k] * sc;
        u16 h = f2bf(s);
        hv[k] = h;
        lv[k] = f2bf(s - bf2f(h));
    }
    *reinterpret_cast<u16x8*>(WH + base + i) = hv;
    *reinterpret_cast<u16x8*>(WL + base + i) = lv;
}

// ---------------------------------------------------------------------------
// Compact Tonnetz mask: weights as bf16 in the 32x32 MFMA S^T D-layout.
// Period 144 in q and k -> 9x9 distinct 64x64 tiles (648 KB, L2-resident).
// ---------------------------------------------------------------------------
__global__ __launch_bounds__(TPB)
void mask_pre(u32* __restrict__ mws)
{
    int bid = blockIdx.x;            // 0..80
    int mq9 = bid / 9, mk9 = bid % 9;
    int t = threadIdx.x, w = t >> 6, l = t & 63, lh = l >> 5, l31 = l & 31;
    int q = mq9 * 16 + (w & 1) * 32 + l31;
    int qx = q % 12, qy = (q / 12) % 12;
    u32 words[8];
    #pragma unroll
    for (int jr = 0; jr < 8; ++jr) {
        u16 wb[2];
        #pragma unroll
        for (int e = 0; e < 2; ++e) {
            int r = jr * 2 + e;
            int key = mk9 * 16 + (w >> 1) * 32 + (r & 3) + 8 * (r >> 2) + 4 * lh;
            int kx = key % 12, ky = (key / 12) % 12;
            int dx = qx - kx; dx = dx < 0 ? -dx : dx; dx = dx < 12 - dx ? dx : 12 - dx;
            int dy = qy - ky; dy = dy < 0 ? -dy : dy; dy = dy < 12 - dy ? dy : 12 - dy;
            int d = dx + dy;
            float wgt = (d <= 2) ? 1.0f : __expf(-(float)d);
            wb[e] = f2bf(wgt);
        }
        words[jr] = (u32)wb[0] | ((u32)wb[1] << 16);
    }
    u32* dst = &mws[(size_t)((bid * 4 + w) * 64 + l) * 8];
    #pragma unroll
    for (int jr = 0; jr < 8; ++jr) dst[jr] = words[jr];
}

// ---------------------------------------------------------------------------
// Split-bf16 GEMM with global_load_lds staging (m97 structure: linear LDS,
// wave w stages array w via 8x async 16B loads; barrier drains vmcnt).
// mode 0: fp32 out [8192][512] (bias b0)
// mode 9: QKV fused (B = [1536][512] concat), proj = n0>>9:
//         0 -> Q hi/lo [b][h][t][d] (bias b0 * QSCALE)
//         1 -> K bf16  [b][h][t][d] (bias b1)
//         2 -> V bf16 transposed [b][h][d][t'] (bias b2), t' = t with bits
//              2<->3 swapped (PV A-fragment key order -> no lane exchange)
// ---------------------------------------------------------------------------
__global__ __launch_bounds__(TPB)
void gemm_pre(const u16* __restrict__ Ah_g, const u16* __restrict__ Al_g,
              const u16* __restrict__ Bh_g, const u16* __restrict__ Bl_g,
              const float* __restrict__ b0, const float* __restrict__ b1,
              const float* __restrict__ b2,
              float* __restrict__ outf, u16* __restrict__ o1h,
              u16* __restrict__ o1l, u16* __restrict__ o2,
              u16* __restrict__ o3, int mode)
{
    __shared__ __align__(16) u16 GL[4][128][32];   // Ah | Al | Bh | Bl (32 KB)

    const int t  = threadIdx.x;
    const int m0 = blockIdx.x * 128;
    const int n0 = blockIdx.y * 128;
    const int wv = t >> 6, l = t & 63, lr = l & 15, lg = l >> 4;
    const int wm = (wv >> 1) * 64, wn = (wv & 1) * 64;

    // staging role: wave wv owns array wv
    const u16* gsrc = (wv == 0) ? Ah_g : (wv == 1) ? Al_g : (wv == 2) ? Bh_g : Bl_g;
    const int rb = (wv < 2) ? m0 : n0;
    const int srow = l >> 2;            // 0..15 within 16-row group
    const int scol = (l & 3) * 8;       // 0..24, 8-el col chunk

    f32x4 acc[4][4];
    #pragma unroll
    for (int i = 0; i < 4; ++i)
        #pragma unroll
        for (int j = 0; j < 4; ++j) acc[i][j] = f32x4{};

    for (int k0 = 0; k0 < 512; k0 += 32) {
        __syncthreads();
        #pragma unroll
        for (int i = 0; i < 8; ++i) {
            int row = i * 16 + srow;
            const u16* g = gsrc + (size_t)(rb + row) * 512 + k0 + scol;
            __builtin_amdgcn_global_load_lds(
                (const __attribute__((address_space(1))) void*)g,
                (__attribute__((address_space(3))) void*)&GL[wv][i * 16][0],
                16, 0, 0);
        }
        __syncthreads();   // drains vmcnt -> staged data visible

        bf16x8 afh[4], afl[4], bfh[4], bfl[4];
        #pragma unroll
        for (int mi = 0; mi < 4; ++mi) {
            afh[mi] = *reinterpret_cast<const bf16x8*>(&GL[0][wm + mi*16 + lr][lg*8]);
            afl[mi] = *reinterpret_cast<const bf16x8*>(&GL[1][wm + mi*16 + lr][lg*8]);
        }
        #pragma unroll
        for (int ni = 0; ni < 4; ++ni) {
            bfh[ni] = *reinterpret_cast<const bf16x8*>(&GL[2][wn + ni*16 + lr][lg*8]);
            bfl[ni] = *reinterpret_cast<const bf16x8*>(&GL[3][wn + ni*16 + lr][lg*8]);
        }
        #pragma unroll
        for (int mi = 0; mi < 4; ++mi)
            #pragma unroll
            for (int ni = 0; ni < 4; ++ni) {
                acc[mi][ni] = MFMA16(afh[mi], bfh[ni], acc[mi][ni]);
                acc[mi][ni] = MFMA16(afh[mi], bfl[ni], acc[mi][ni]);
                acc[mi][ni] = MFMA16(afl[mi], bfh[ni], acc[mi][ni]);
            }
    }

    // epilogue: D frag -> (row = mi*16 + lg*4 + j, col = ni*16 + lr)
    int emode = mode;
    const float* bias = b0;
    float bsc = 1.0f;
    if (mode == 9) {
        int proj = n0 >> 9;
        emode = (proj == 0) ? 1 : (proj == 1) ? 2 : 3;
        bias = (proj == 0) ? b0 : (proj == 1) ? b1 : b2;
        bsc = (proj == 0) ? QSCALE : 1.0f;
    }
    #pragma unroll
    for (int ni = 0; ni < 4; ++ni) {
        int gn = n0 + wn + ni*16 + lr;
        int nn = gn & 511;
        float bb = bias[nn] * bsc;
        #pragma unroll
        for (int mi = 0; mi < 4; ++mi) {
            #pragma unroll
            for (int j = 0; j < 4; ++j) {
                int gm = m0 + wm + mi*16 + lg*4 + j;
                float v = acc[mi][ni][j] + bb;
                if (emode == 0) {
                    outf[(size_t)gm * 512 + gn] = v;
                } else {
                    int b = gm >> 11, tt = gm & 2047, hh = nn >> 6, d = nn & 63;
                    if (emode == 1) {
                        u16 h16 = f2bf(v);
                        size_t o = (((size_t)(b*8 + hh) * 2048) + tt) * 64 + d;
                        o1h[o] = h16;
                        o1l[o] = f2bf(v - bf2f(h16));
                    } else if (emode == 2) {
                        o2[(((size_t)(b*8 + hh) * 2048) + tt) * 64 + d] = f2bf(v);
                    } else {
                        // V: permute key order (swap bits 2<->3 of t) so PV
                        // A-fragments need no lane half-exchange in attn.
                        int ttp = (tt & ~12) | ((tt & 4) << 1) | ((tt & 8) >> 1);
                        o3[(((size_t)(b*8 + hh) * 64) + d) * 2048 + ttp] = f2bf(v);
                    }
                }
            }
        }
    }
}

// ---------------------------------------------------------------------------
// Flash attention (round-9 staged/dbuf structure) with:
//  - V key-permuted in memory -> PV A-fragment = lane's own p regs packed
//    directly (no shfl_xor, no selects on the critical path)
//  - QK^T split into two 4-deep MFMA chains (hi / lo), summed at exp time
// ---------------------------------------------------------------------------
__device__ __forceinline__ int lidx(int row, int col) {    // col multiple of 8
    return row * 64 + (col ^ ((row & 7) << 3));
}

__global__ __launch_bounds__(ATPB)
void attn32(const u16* __restrict__ Qh_g, const u16* __restrict__ Ql_g,
            const u16* __restrict__ K_g,  const u16* __restrict__ Vt_g,
            const u32* __restrict__ mws,
            u16* __restrict__ AOh, u16* __restrict__ AOl)
{
    __shared__ __align__(16) u16 SMEM[16384];   // KS dbuf | VS dbuf; reused as OSC (32 KB)
    __shared__ float SC[8][64];
    __shared__ float ILS[128];
    u16* KS0 = SMEM;            // [2][4096]
    u16* VS0 = SMEM + 8192;     // [2][4096]

    const int t = threadIdx.x;
    int id  = blockIdx.x;                 // 512 blocks: 8 XCD x 4 bh x 16 q-tiles
    int xcd = id & 7, seq = id >> 3;
    int bh  = xcd * 4 + (seq >> 4);
    int qt  = seq & 15;
    const int q0 = qt * 128;
    const int b = bh >> 3, h = bh & 7;
    const int w = t >> 6, l = t & 63, lh = l >> 5, l31 = l & 31;
    const int qg = w >> 1, kh = w & 1;
    const int mq9 = ((q0 + qg * 32) % 144) >> 4;

    // Q B-fragments in registers: col q = q0 + qg*32 + l31, k = ks*16 + lh*8 + j
    const u16* Qhb = Qh_g + ((size_t)bh * 2048 + q0 + qg * 32 + l31) * 64;
    const u16* Qlb = Ql_g + ((size_t)bh * 2048 + q0 + qg * 32 + l31) * 64;
    bf16x8 qfh[4], qfl[4];
    #pragma unroll
    for (int ks = 0; ks < 4; ++ks) {
        qfh[ks] = *reinterpret_cast<const bf16x8*>(&Qhb[ks * 16 + lh * 8]);
        qfl[ks] = *reinterpret_cast<const bf16x8*>(&Qlb[ks * 16 + lh * 8]);
    }

    const u16* Kb = K_g  + (size_t)bh * 2048 * 64;
    const u16* Vb = Vt_g + (size_t)bh * 64 * 2048;
    const int sr = t >> 3, sc8 = (t & 7) * 8;   // staging: 1 K slot + 1 V slot / thread

    // prologue: tile0 -> buf0, prefetch tile1 into regs
    bf16x8 kst = *reinterpret_cast<const bf16x8*>(&Kb[(size_t)sr * 64 + sc8]);
    bf16x8 vst = *reinterpret_cast<const bf16x8*>(&Vb[(size_t)sr * 2048 + sc8]);
    *reinterpret_cast<bf16x8*>(&KS0[lidx(sr, sc8)]) = kst;
    *reinterpret_cast<bf16x8*>(&VS0[lidx(sr, sc8)]) = vst;
    kst = *reinterpret_cast<const bf16x8*>(&Kb[(size_t)(64 + sr) * 64 + sc8]);
    vst = *reinterpret_cast<const bf16x8*>(&Vb[(size_t)sr * 2048 + 64 + sc8]);
    __syncthreads();

    f32x16 o0 = {}, o1 = {};
    float lrow = 0.f;

    for (int kt = 0; kt < 32; ++kt) {
        const int cur = kt & 1;

        // mask load (L2-resident; consumed after QK^T); slot = kh<<1
        int mk9 = (4 * kt) % 9;
        const u32* mp = &mws[(size_t)((((mq9 * 9 + mk9) * 4 + (kh << 1)) * 64 + l)) * 8];
        u32x4 mwa = *reinterpret_cast<const u32x4*>(mp);
        u32x4 mwb = *reinterpret_cast<const u32x4*>(mp + 4);

        // S^T = K Qh^T  and  K Ql^T as two independent 4-deep chains
        f32x16 sth = {}, stl = {};
        __builtin_amdgcn_s_setprio(1);
        #pragma unroll
        for (int ks = 0; ks < 4; ++ks) {
            bf16x8 kf = *reinterpret_cast<const bf16x8*>(&KS0[cur * 4096 + lidx(kh * 32 + l31, ks * 16 + lh * 8)]);
            sth = MFMA32(kf, qfh[ks], sth);
            stl = MFMA32(kf, qfl[ks], stl);
        }
        __builtin_amdgcn_s_setprio(0);

        // stage next tile into the other buffer; prefetch tile kt+2
        if (kt < 31) {
            *reinterpret_cast<bf16x8*>(&KS0[(cur ^ 1) * 4096 + lidx(sr, sc8)]) = kst;
            *reinterpret_cast<bf16x8*>(&VS0[(cur ^ 1) * 4096 + lidx(sr, sc8)]) = vst;
        }
        if (kt < 30) {
            int k0n = (kt + 2) * 64;
            kst = *reinterpret_cast<const bf16x8*>(&Kb[(size_t)(k0n + sr) * 64 + sc8]);
            vst = *reinterpret_cast<const bf16x8*>(&Vb[(size_t)sr * 2048 + k0n + sc8]);
        }

        // p = exp2((sh+sl) * w), bf16 weights unpacked from packed words
        float p[16];
        #pragma unroll
        for (int r = 0; r < 16; ++r) {
            u32 word = (r < 8) ? mwa[r >> 1] : mwb[(r >> 1) - 4];
            u32 bits = (r & 1) ? (word & 0xFFFF0000u) : (word << 16);
            float wgt = __uint_as_float(bits);
            p[r] = exp2f((sth[r] + stl[r]) * wgt);
            lrow += p[r];
        }

        // PV: pack P -> A-fragment DIRECTLY (V key order permuted in memory)
        __builtin_amdgcn_s_setprio(1);
        #pragma unroll
        for (int ks = 0; ks < 2; ++ks) {
            const int base = ks * 8;
            u32 pk01, pk23, pk45, pk67;
            asm("v_cvt_pk_bf16_f32 %0, %1, %2" : "=v"(pk01) : "v"(p[base + 0]), "v"(p[base + 1]));
            asm("v_cvt_pk_bf16_f32 %0, %1, %2" : "=v"(pk23) : "v"(p[base + 2]), "v"(p[base + 3]));
            asm("v_cvt_pk_bf16_f32 %0, %1, %2" : "=v"(pk45) : "v"(p[base + 4]), "v"(p[base + 5]));
            asm("v_cvt_pk_bf16_f32 %0, %1, %2" : "=v"(pk67) : "v"(p[base + 6]), "v"(p[base + 7]));
            u32x4 pw = {pk01, pk23, pk45, pk67};
            bf16x8 pa = __builtin_bit_cast(bf16x8, pw);
            bf16x8 v0 = *reinterpret_cast<const bf16x8*>(&VS0[cur * 4096 + lidx(l31,      kh * 32 + ks * 16 + lh * 8)]);
            bf16x8 v1 = *reinterpret_cast<const bf16x8*>(&VS0[cur * 4096 + lidx(32 + l31, kh * 32 + ks * 16 + lh * 8)]);
            o0 = MFMA32(pa, v0, o0);
            o1 = MFMA32(pa, v1, o1);
        }
        __builtin_amdgcn_s_setprio(0);
        __syncthreads();
    }

    // ---- merge: lrow across (lane-half, key-half); O across key-halves ----
    SC[w][l] = lrow;
    __syncthreads();
    float* OSC = (float*)SMEM;                    // [128 q][64 d] = 32 KB
    if (kh == 1) {
        #pragma unroll
        for (int r = 0; r < 16; ++r) {
            int q = qg * 32 + (r & 3) + 8 * (r >> 2) + 4 * lh;
            OSC[q * 64 + l31]      = o0[r];
            OSC[q * 64 + 32 + l31] = o1[r];
        }
    } else if (l < 32) {
        float s = SC[qg*2][l31] + SC[qg*2][l31 + 32] + SC[qg*2 + 1][l31] + SC[qg*2 + 1][l31 + 32];
        ILS[qg * 32 + l31] = 1.0f / s;
    }
    __syncthreads();
    if (kh == 0) {
        #pragma unroll
        for (int r = 0; r < 16; ++r) {
            int q = qg * 32 + (r & 3) + 8 * (r >> 2) + 4 * lh;
            float il = ILS[q];
            float v0 = (o0[r] + OSC[q * 64 + l31]) * il;
            float v1 = (o1[r] + OSC[q * 64 + 32 + l31]) * il;
            size_t row = (size_t)b * 2048 + q0 + q;
            size_t off0 = row * 512 + h * 64 + l31;
            u16 h0v = f2bf(v0);
            AOh[off0] = h0v;
            AOl[off0] = f2bf(v0 - bf2f(h0v));
            u16 h1v = f2bf(v1);
            AOh[off0 + 32] = h1v;
            AOl[off0 + 32] = f2bf(v1 - bf2f(h1v));
        }
    }
}

// ---------------------------------------------------------------------------
extern "C" void kernel_launch(void* const* d_in, const int* in_sizes, int n_in,
                              void* d_out, int out_size, void* d_ws, size_t ws_size,
                              hipStream_t stream)
{
    (void)in_sizes; (void)n_in; (void)out_size; (void)ws_size;
    const float* x  = (const float*)d_in[0];
    const float* Wq = (const float*)d_in[1];
    const float* bq = (const float*)d_in[2];
    const float* Wk = (const float*)d_in[3];
    const float* bk = (const float*)d_in[4];
    const float* Wv = (const float*)d_in[5];
    const float* bv = (const float*)d_in[6];
    const float* Wo = (const float*)d_in[7];
    const float* bo = (const float*)d_in[8];
    float* out = (float*)d_out;

    // workspace (~53 MB of >=64 MB proven):
    u16* Xh = (u16*)d_ws;                 // 8 MB (reused as AOh)
    u16* Xl = Xh + 4194304;               // 8 MB (reused as AOl)
    u16* WH = Xl + 4194304;               // 2 MB
    u16* WL = WH + 1048576;               // 2 MB
    u16* Qh = WL + 1048576;               // 8 MB
    u16* Ql = Qh + 4194304;               // 8 MB
    u16* Kh = Ql + 4194304;               // 8 MB
    u16* Vt = Kh + 4194304;               // 8 MB (key-permuted layout)
    u32* MW = (u32*)(Vt + 4194304);       // 648 KB (bf16 compact mask)

    presplit<<<2048, TPB, 0, stream>>>(x, Xh, Xl, 1.0f);
    presplit_w<<<dim3(128, 4), TPB, 0, stream>>>(Wq, Wk, Wv, Wo, WH, WL);
    mask_pre<<<81, TPB, 0, stream>>>(MW);

    // fused QKV projection: 768 blocks, 32 KB LDS
    gemm_pre<<<dim3(64, 12), TPB, 0, stream>>>(
        Xh, Xl, WH, WL, bq, bk, bv,
        nullptr, Qh, Ql, Kh, Vt, 9);

    // 8-wave attention: 512 blocks x 512 threads
    attn32<<<512, ATPB, 0, stream>>>(Qh, Ql, Kh, Vt, MW, Xh, Xl);

    // output projection
    gemm_pre<<<dim3(64, 4), TPB, 0, stream>>>(
        Xh, Xl, WH + 786432, WL + 786432, bo, nullptr, nullptr,
        out, nullptr, nullptr, nullptr, nullptr, 0);
}

// Round 12
// 134.206 us; speedup vs baseline: 1.7821x; 1.4367x over previous
//
#include <hip/hip_runtime.h>
#include <math.h>

#define TPB 256
#define ATPB 512
#define QSCALE 0.1803368801111204f   // 0.125 * log2(e): folds 1/sqrt(dk) and exp->exp2

typedef __attribute__((ext_vector_type(8))) _Float16 f16x8;
typedef __attribute__((ext_vector_type(8))) unsigned short u16x8;
typedef __attribute__((ext_vector_type(4))) float f32x4;
typedef __attribute__((ext_vector_type(16))) float f32x16;
typedef __attribute__((ext_vector_type(4))) unsigned int u32x4;
typedef unsigned short u16;
typedef unsigned int u32;

#define MFMA16F(a, b, c) __builtin_amdgcn_mfma_f32_16x16x32_f16((a), (b), (c), 0, 0, 0)
#define MFMA32F(a, b, c) __builtin_amdgcn_mfma_f32_32x32x16_f16((a), (b), (c), 0, 0, 0)

__device__ __forceinline__ u16 f2h(float f) {
    return __builtin_bit_cast(u16, (_Float16)f);
}
__device__ __forceinline__ u16 f2bf(float f) {           // RNE (mask table only)
    unsigned int u = __float_as_uint(f);
    return (u16)((u + 0x7FFFu + ((u >> 16) & 1u)) >> 16);
}

// ---------------------------------------------------------------------------
// X fp32 -> single fp16. 8 elems/thread.
// ---------------------------------------------------------------------------
__global__ __launch_bounds__(TPB)
void cvt_x(const float* __restrict__ in, u16* __restrict__ o)
{
    size_t i = ((size_t)blockIdx.x * TPB + threadIdx.x) * 8;
    float4 a = *reinterpret_cast<const float4*>(in + i);
    float4 b = *reinterpret_cast<const float4*>(in + i + 4);
    float v[8] = {a.x, a.y, a.z, a.w, b.x, b.y, b.z, b.w};
    u16x8 hv;
    #pragma unroll
    for (int k = 0; k < 8; ++k) hv[k] = f2h(v[k]);
    *reinterpret_cast<u16x8*>(o + i) = hv;
}

// weights: Wq*QSCALE, Wk, Wv -> single fp16 concat [1536][512]; Wo -> hi/lo fp16
__global__ __launch_bounds__(TPB)
void presplit_w(const float* __restrict__ w0, const float* __restrict__ w1,
                const float* __restrict__ w2, const float* __restrict__ w3,
                u16* __restrict__ WS, u16* __restrict__ WOh, u16* __restrict__ WOl)
{
    int y = blockIdx.y;
    const float* src = (y == 0) ? w0 : (y == 1) ? w1 : (y == 2) ? w2 : w3;
    float sc = (y == 0) ? QSCALE : 1.0f;
    size_t i = ((size_t)blockIdx.x * TPB + threadIdx.x) * 8;
    float4 a = *reinterpret_cast<const float4*>(src + i);
    float4 b = *reinterpret_cast<const float4*>(src + i + 4);
    float v[8] = {a.x, a.y, a.z, a.w, b.x, b.y, b.z, b.w};
    if (y < 3) {
        size_t base = (size_t)y * 262144;
        u16x8 hv;
        #pragma unroll
        for (int k = 0; k < 8; ++k) hv[k] = f2h(v[k] * sc);
        *reinterpret_cast<u16x8*>(WS + base + i) = hv;
    } else {
        u16x8 hv, lv;
        #pragma unroll
        for (int k = 0; k < 8; ++k) {
            _Float16 h = (_Float16)v[k];
            hv[k] = __builtin_bit_cast(u16, h);
            lv[k] = f2h(v[k] - (float)h);
        }
        *reinterpret_cast<u16x8*>(WOh + i) = hv;
        *reinterpret_cast<u16x8*>(WOl + i) = lv;
    }
}

// ---------------------------------------------------------------------------
// Compact Tonnetz mask: bf16 weights in the 32x32 MFMA S^T D-layout (proven).
// ---------------------------------------------------------------------------
__global__ __launch_bounds__(TPB)
void mask_pre(u32* __restrict__ mws)
{
    int bid = blockIdx.x;            // 0..80
    int mq9 = bid / 9, mk9 = bid % 9;
    int t = threadIdx.x, w = t >> 6, l = t & 63, lh = l >> 5, l31 = l & 31;
    int q = mq9 * 16 + (w & 1) * 32 + l31;
    int qx = q % 12, qy = (q / 12) % 12;
    u32 words[8];
    #pragma unroll
    for (int jr = 0; jr < 8; ++jr) {
        u16 wb[2];
        #pragma unroll
        for (int e = 0; e < 2; ++e) {
            int r = jr * 2 + e;
            int key = mk9 * 16 + (w >> 1) * 32 + (r & 3) + 8 * (r >> 2) + 4 * lh;
            int kx = key % 12, ky = (key / 12) % 12;
            int dx = qx - kx; dx = dx < 0 ? -dx : dx; dx = dx < 12 - dx ? dx : 12 - dx;
            int dy = qy - ky; dy = dy < 0 ? -dy : dy; dy = dy < 12 - dy ? dy : 12 - dy;
            int d = dx + dy;
            float wgt = (d <= 2) ? 1.0f : __expf(-(float)d);
            wb[e] = f2bf(wgt);
        }
        words[jr] = (u32)wb[0] | ((u32)wb[1] << 16);
    }
    u32* dst = &mws[(size_t)((bid * 4 + w) * 64 + l) * 8];
    #pragma unroll
    for (int jr = 0; jr < 8; ++jr) dst[jr] = words[jr];
}

// ---------------------------------------------------------------------------
// Single-precision fp16 QKV GEMM (output quantized to fp16 anyway).
// A = Xf [8192][512] f16, B = Wc [1536][512] f16 (Wq pre-scaled by QSCALE).
// global_load_lds staging with bank-conflict XOR swizzle (rule #21: linear
// LDS dest + inverse-swizzled GLOBAL source + swizzled read; read-side XOR
// is a per-lane constant lg ^ ((lr>>1)&3)).
// Epilogue by proj = n0>>9: 0 -> Q f16 [b][h][t][d] (bias*QSCALE)
//                           1 -> K f16 [b][h][t][d]
//                           2 -> V f16 [b][h][d][t'], t' = t bits2<->3 swap
// ---------------------------------------------------------------------------
__global__ __launch_bounds__(TPB)
void gemm_qkv(const u16* __restrict__ Xf, const u16* __restrict__ Wc,
              const float* __restrict__ bq, const float* __restrict__ bk,
              const float* __restrict__ bv,
              u16* __restrict__ Qf, u16* __restrict__ Kf, u16* __restrict__ Vt)
{
    __shared__ __align__(16) u16 XS[128][32];
    __shared__ __align__(16) u16 WSs[128][32];

    const int t  = threadIdx.x;
    const int m0 = blockIdx.x * 128;
    const int n0 = blockIdx.y * 128;
    const int wv = t >> 6, l = t & 63, lr = l & 15, lg = l >> 4;
    const int wm = (wv >> 1) * 64, wn = (wv & 1) * 64;

    const u16* gsrc = (wv < 2) ? Xf : Wc;
    const int rbase = (wv < 2) ? m0 : n0;
    const int rgrp  = (wv & 1) * 64;
    const int srow  = l >> 2;
    const int scol  = ((l & 3) ^ ((l >> 3) & 3)) * 8;   // inverse-swizzled source
    u16 (*dst)[32] = (wv < 2) ? XS : WSs;

    const int swc = (lg ^ ((lr >> 1) & 3)) * 8;         // swizzled read col

    f32x4 acc[4][4];
    #pragma unroll
    for (int i = 0; i < 4; ++i)
        #pragma unroll
        for (int j = 0; j < 4; ++j) acc[i][j] = f32x4{};

    for (int k0 = 0; k0 < 512; k0 += 32) {
        __syncthreads();
        #pragma unroll
        for (int j = 0; j < 4; ++j) {
            int row0 = rgrp + j * 16;
            const u16* g = gsrc + (size_t)(rbase + row0 + srow) * 512 + k0 + scol;
            __builtin_amdgcn_global_load_lds(
                (const __attribute__((address_space(1))) void*)g,
                (__attribute__((address_space(3))) void*)&dst[row0][0],
                16, 0, 0);
        }
        __syncthreads();

        f16x8 af[4], bfr[4];
        #pragma unroll
        for (int mi = 0; mi < 4; ++mi)
            af[mi] = *reinterpret_cast<const f16x8*>(&XS[wm + mi*16 + lr][swc]);
        #pragma unroll
        for (int ni = 0; ni < 4; ++ni)
            bfr[ni] = *reinterpret_cast<const f16x8*>(&WSs[wn + ni*16 + lr][swc]);
        #pragma unroll
        for (int mi = 0; mi < 4; ++mi)
            #pragma unroll
            for (int ni = 0; ni < 4; ++ni)
                acc[mi][ni] = MFMA16F(af[mi], bfr[ni], acc[mi][ni]);
    }

    const int proj = n0 >> 9;
    const float* bias = (proj == 0) ? bq : (proj == 1) ? bk : bv;
    const float bsc = (proj == 0) ? QSCALE : 1.0f;
    #pragma unroll
    for (int ni = 0; ni < 4; ++ni) {
        int gn = n0 + wn + ni*16 + lr;
        int nn = gn & 511;
        float bb = bias[nn] * bsc;
        #pragma unroll
        for (int mi = 0; mi < 4; ++mi) {
            #pragma unroll
            for (int j = 0; j < 4; ++j) {
                int gm = m0 + wm + mi*16 + lg*4 + j;
                float v = acc[mi][ni][j] + bb;
                int b = gm >> 11, tt = gm & 2047, hh = nn >> 6, d = nn & 63;
                if (proj == 0) {
                    Qf[(((size_t)(b*8 + hh) * 2048) + tt) * 64 + d] = f2h(v);
                } else if (proj == 1) {
                    Kf[(((size_t)(b*8 + hh) * 2048) + tt) * 64 + d] = f2h(v);
                } else {
                    int ttp = (tt & ~12) | ((tt & 4) << 1) | ((tt & 8) >> 1);
                    Vt[(((size_t)(b*8 + hh) * 64) + d) * 2048 + ttp] = f2h(v);
                }
            }
        }
    }
}

// ---------------------------------------------------------------------------
// 3-term fp16 out-projection GEMM (final fp32 output): A = AO hi/lo,
// B = Wo hi/lo. Same gload_lds + swizzle staging; wave wv stages array wv.
// ---------------------------------------------------------------------------
__global__ __launch_bounds__(TPB)
void gemm_o3(const u16* __restrict__ Ah_g, const u16* __restrict__ Al_g,
             const u16* __restrict__ Bh_g, const u16* __restrict__ Bl_g,
             const float* __restrict__ b0, float* __restrict__ outf)
{
    __shared__ __align__(16) u16 GL[4][128][32];

    const int t  = threadIdx.x;
    const int m0 = blockIdx.x * 128;
    const int n0 = blockIdx.y * 128;
    const int wv = t >> 6, l = t & 63, lr = l & 15, lg = l >> 4;
    const int wm = (wv >> 1) * 64, wn = (wv & 1) * 64;

    const u16* gsrc = (wv == 0) ? Ah_g : (wv == 1) ? Al_g : (wv == 2) ? Bh_g : Bl_g;
    const int rbase = (wv < 2) ? m0 : n0;
    const int srow  = l >> 2;
    const int scol  = ((l & 3) ^ ((l >> 3) & 3)) * 8;
    const int swc   = (lg ^ ((lr >> 1) & 3)) * 8;

    f32x4 acc[4][4];
    #pragma unroll
    for (int i = 0; i < 4; ++i)
        #pragma unroll
        for (int j = 0; j < 4; ++j) acc[i][j] = f32x4{};

    for (int k0 = 0; k0 < 512; k0 += 32) {
        __syncthreads();
        #pragma unroll
        for (int j = 0; j < 8; ++j) {
            int row0 = j * 16;
            const u16* g = gsrc + (size_t)(rbase + row0 + srow) * 512 + k0 + scol;
            __builtin_amdgcn_global_load_lds(
                (const __attribute__((address_space(1))) void*)g,
                (__attribute__((address_space(3))) void*)&GL[wv][row0][0],
                16, 0, 0);
        }
        __syncthreads();

        f16x8 afh[4], afl[4], bfh[4], bfl[4];
        #pragma unroll
        for (int mi = 0; mi < 4; ++mi) {
            afh[mi] = *reinterpret_cast<const f16x8*>(&GL[0][wm + mi*16 + lr][swc]);
            afl[mi] = *reinterpret_cast<const f16x8*>(&GL[1][wm + mi*16 + lr][swc]);
        }
        #pragma unroll
        for (int ni = 0; ni < 4; ++ni) {
            bfh[ni] = *reinterpret_cast<const f16x8*>(&GL[2][wn + ni*16 + lr][swc]);
            bfl[ni] = *reinterpret_cast<const f16x8*>(&GL[3][wn + ni*16 + lr][swc]);
        }
        #pragma unroll
        for (int mi = 0; mi < 4; ++mi)
            #pragma unroll
            for (int ni = 0; ni < 4; ++ni) {
                acc[mi][ni] = MFMA16F(afh[mi], bfh[ni], acc[mi][ni]);
                acc[mi][ni] = MFMA16F(afh[mi], bfl[ni], acc[mi][ni]);
                acc[mi][ni] = MFMA16F(afl[mi], bfh[ni], acc[mi][ni]);
            }
    }

    #pragma unroll
    for (int ni = 0; ni < 4; ++ni) {
        int gn = n0 + wn + ni*16 + lr;
        float bb = b0[gn];
        #pragma unroll
        for (int mi = 0; mi < 4; ++mi) {
            #pragma unroll
            for (int j = 0; j < 4; ++j) {
                int gm = m0 + wm + mi*16 + lg*4 + j;
                outf[(size_t)gm * 512 + gn] = acc[mi][ni][j] + bb;
            }
        }
    }
}

// ---------------------------------------------------------------------------
// Flash attention: Q/K/V/P single fp16 (QK = 4 MFMA32/tile, was 8).
// Round-9 staged/dbuf structure; V key-permuted (direct P pack); bf16 mask
// table unchanged. AO written as hi/lo fp16 for the 3-term out-projection.
// ---------------------------------------------------------------------------
__device__ __forceinline__ int lidx(int row, int col) {    // col multiple of 8
    return row * 64 + (col ^ ((row & 7) << 3));
}

__global__ __launch_bounds__(ATPB)
void attn32(const u16* __restrict__ Qf_g, const u16* __restrict__ K_g,
            const u16* __restrict__ Vt_g, const u32* __restrict__ mws,
            u16* __restrict__ AOh, u16* __restrict__ AOl)
{
    __shared__ __align__(16) u16 SMEM[16384];   // KS dbuf | VS dbuf; reused as OSC
    __shared__ float SC[8][64];
    __shared__ float ILS[128];
    u16* KS0 = SMEM;            // [2][4096]
    u16* VS0 = SMEM + 8192;     // [2][4096]

    const int t = threadIdx.x;
    int id  = blockIdx.x;                 // 512 blocks: 8 XCD x 4 bh x 16 q-tiles
    int xcd = id & 7, seq = id >> 3;
    int bh  = xcd * 4 + (seq >> 4);
    int qt  = seq & 15;
    const int q0 = qt * 128;
    const int b = bh >> 3, h = bh & 7;
    const int w = t >> 6, l = t & 63, lh = l >> 5, l31 = l & 31;
    const int qg = w >> 1, kh = w & 1;
    const int mq9 = ((q0 + qg * 32) % 144) >> 4;

    // Q B-fragments (single fp16): col q = q0 + qg*32 + l31, k = ks*16 + lh*8 + j
    const u16* Qfb = Qf_g + ((size_t)bh * 2048 + q0 + qg * 32 + l31) * 64;
    f16x8 qf[4];
    #pragma unroll
    for (int ks = 0; ks < 4; ++ks)
        qf[ks] = *reinterpret_cast<const f16x8*>(&Qfb[ks * 16 + lh * 8]);

    const u16* Kb = K_g  + (size_t)bh * 2048 * 64;
    const u16* Vb = Vt_g + (size_t)bh * 64 * 2048;
    const int sr = t >> 3, sc8 = (t & 7) * 8;

    // prologue: tile0 -> buf0, prefetch tile1 into regs
    u16x8 kst = *reinterpret_cast<const u16x8*>(&Kb[(size_t)sr * 64 + sc8]);
    u16x8 vst = *reinterpret_cast<const u16x8*>(&Vb[(size_t)sr * 2048 + sc8]);
    *reinterpret_cast<u16x8*>(&KS0[lidx(sr, sc8)]) = kst;
    *reinterpret_cast<u16x8*>(&VS0[lidx(sr, sc8)]) = vst;
    kst = *reinterpret_cast<const u16x8*>(&Kb[(size_t)(64 + sr) * 64 + sc8]);
    vst = *reinterpret_cast<const u16x8*>(&Vb[(size_t)sr * 2048 + 64 + sc8]);
    __syncthreads();

    f32x16 o0 = {}, o1 = {};
    float lrow = 0.f;

    for (int kt = 0; kt < 32; ++kt) {
        const int cur = kt & 1;

        // mask load (L2-resident; consumed after QK^T)
        int mk9 = (4 * kt) % 9;
        const u32* mp = &mws[(size_t)((((mq9 * 9 + mk9) * 4 + (kh << 1)) * 64 + l)) * 8];
        u32x4 mwa = *reinterpret_cast<const u32x4*>(mp);
        u32x4 mwb = *reinterpret_cast<const u32x4*>(mp + 4);

        // S^T = K Q^T (single chain, 4 MFMA32)
        f32x16 st = {};
        __builtin_amdgcn_s_setprio(1);
        #pragma unroll
        for (int ks = 0; ks < 4; ++ks) {
            f16x8 kf = *reinterpret_cast<const f16x8*>(&KS0[cur * 4096 + lidx(kh * 32 + l31, ks * 16 + lh * 8)]);
            st = MFMA32F(kf, qf[ks], st);
        }
        __builtin_amdgcn_s_setprio(0);

        // stage next tile into the other buffer; prefetch tile kt+2
        if (kt < 31) {
            *reinterpret_cast<u16x8*>(&KS0[(cur ^ 1) * 4096 + lidx(sr, sc8)]) = kst;
            *reinterpret_cast<u16x8*>(&VS0[(cur ^ 1) * 4096 + lidx(sr, sc8)]) = vst;
        }
        if (kt < 30) {
            int k0n = (kt + 2) * 64;
            kst = *reinterpret_cast<const u16x8*>(&Kb[(size_t)(k0n + sr) * 64 + sc8]);
            vst = *reinterpret_cast<const u16x8*>(&Vb[(size_t)sr * 2048 + k0n + sc8]);
        }

        // p = exp2(s * w); bf16 mask weights unpacked by shift
        float p[16];
        #pragma unroll
        for (int r = 0; r < 16; ++r) {
            u32 word = (r < 8) ? mwa[r >> 1] : mwb[(r >> 1) - 4];
            u32 bits = (r & 1) ? (word & 0xFFFF0000u) : (word << 16);
            float wgt = __uint_as_float(bits);
            p[r] = exp2f(st[r] * wgt);
            lrow += p[r];
        }

        // PV: quantize P to fp16 in-register (RNE, unbiased) -> direct A-frag
        __builtin_amdgcn_s_setprio(1);
        #pragma unroll
        for (int ks = 0; ks < 2; ++ks) {
            const int base = ks * 8;
            f16x8 pa;
            #pragma unroll
            for (int j = 0; j < 8; ++j) pa[j] = (_Float16)p[base + j];
            f16x8 v0 = *reinterpret_cast<const f16x8*>(&VS0[cur * 4096 + lidx(l31,      kh * 32 + ks * 16 + lh * 8)]);
            f16x8 v1 = *reinterpret_cast<const f16x8*>(&VS0[cur * 4096 + lidx(32 + l31, kh * 32 + ks * 16 + lh * 8)]);
            o0 = MFMA32F(pa, v0, o0);
            o1 = MFMA32F(pa, v1, o1);
        }
        __builtin_amdgcn_s_setprio(0);
        __syncthreads();
    }

    // ---- merge: lrow across (lane-half, key-half); O across key-halves ----
    SC[w][l] = lrow;
    __syncthreads();
    float* OSC = (float*)SMEM;                    // [128 q][64 d] = 32 KB
    if (kh == 1) {
        #pragma unroll
        for (int r = 0; r < 16; ++r) {
            int q = qg * 32 + (r & 3) + 8 * (r >> 2) + 4 * lh;
            OSC[q * 64 + l31]      = o0[r];
            OSC[q * 64 + 32 + l31] = o1[r];
        }
    } else if (l < 32) {
        float s = SC[qg*2][l31] + SC[qg*2][l31 + 32] + SC[qg*2 + 1][l31] + SC[qg*2 + 1][l31 + 32];
        ILS[qg * 32 + l31] = 1.0f / s;
    }
    __syncthreads();
    if (kh == 0) {
        #pragma unroll
        for (int r = 0; r < 16; ++r) {
            int q = qg * 32 + (r & 3) + 8 * (r >> 2) + 4 * lh;
            float il = ILS[q];
            float v0 = (o0[r] + OSC[q * 64 + l31]) * il;
            float v1 = (o1[r] + OSC[q * 64 + 32 + l31]) * il;
            size_t row = (size_t)b * 2048 + q0 + q;
            size_t off0 = row * 512 + h * 64 + l31;
            _Float16 h0 = (_Float16)v0;
            AOh[off0] = __builtin_bit_cast(u16, h0);
            AOl[off0] = f2h(v0 - (float)h0);
            _Float16 h1 = (_Float16)v1;
            AOh[off0 + 32] = __builtin_bit_cast(u16, h1);
            AOl[off0 + 32] = f2h(v1 - (float)h1);
        }
    }
}

// ---------------------------------------------------------------------------
extern "C" void kernel_launch(void* const* d_in, const int* in_sizes, int n_in,
                              void* d_out, int out_size, void* d_ws, size_t ws_size,
                              hipStream_t stream)
{
    (void)in_sizes; (void)n_in; (void)out_size; (void)ws_size;
    const float* x  = (const float*)d_in[0];
    const float* Wq = (const float*)d_in[1];
    const float* bq = (const float*)d_in[2];
    const float* Wk = (const float*)d_in[3];
    const float* bk = (const float*)d_in[4];
    const float* Wv = (const float*)d_in[5];
    const float* bv = (const float*)d_in[6];
    const float* Wo = (const float*)d_in[7];
    const float* bo = (const float*)d_in[8];
    float* out = (float*)d_out;

    // workspace (~43 MB):
    u16* Xf  = (u16*)d_ws;                // 8 MB (reused as AOh after QKV)
    u16* AOl = Xf + 4194304;              // 8 MB
    u16* WS  = AOl + 4194304;             // 1.5 MB ([1536][512] f16, Wq*QSCALE)
    u16* WOh = WS + 786432;               // 0.5 MB
    u16* WOl = WOh + 262144;              // 0.5 MB
    u16* Qf  = WOl + 262144;              // 8 MB
    u16* Kf  = Qf + 4194304;              // 8 MB
    u16* Vt  = Kf + 4194304;              // 8 MB (key-permuted transposed)
    u32* MW  = (u32*)(Vt + 4194304);      // 648 KB (bf16 compact mask)
    u16* AOh = Xf;

    cvt_x<<<2048, TPB, 0, stream>>>(x, Xf);
    presplit_w<<<dim3(128, 4), TPB, 0, stream>>>(Wq, Wk, Wv, Wo, WS, WOh, WOl);
    mask_pre<<<81, TPB, 0, stream>>>(MW);

    // fused QKV projection, single-precision fp16: 768 blocks, 16 KB LDS
    gemm_qkv<<<dim3(64, 12), TPB, 0, stream>>>(Xf, WS, bq, bk, bv, Qf, Kf, Vt);

    // 8-wave attention: 512 blocks x 512 threads
    attn32<<<512, ATPB, 0, stream>>>(Qf, Kf, Vt, MW, AOh, AOl);

    // output projection (3-term fp16, fp32 out)
    gemm_o3<<<dim3(64, 4), TPB, 0, stream>>>(AOh, AOl, WOh, WOl, bo, out);
}